// Round 8
// baseline (168.827 us; speedup 1.0000x reference)
//
#include <hip/hip_runtime.h>
#include <hip/hip_bf16.h>

constexpr int NB   = 2;
constexpr int CIN  = 128;
constexpr int TT   = 8;
constexpr int HH   = 56;
constexpr int WW   = 56;
constexpr int S    = TT * HH * WW;      // 25088
constexpr int DK   = 16;
constexpr int DV   = 128;
constexpr int TAPS = 147;               // 3*7*7
constexpr int NOUT = DK + DV;           // 144
// padded channel-last v: [b][t:10][h:62][w:62][c:128]
constexpr int VPT = 10, VPH = 62, VPW = 62;
constexpr int PCELLS = NB * VPT * VPH * VPW;   // 76880 padded cells
constexpr int WROWS = 21;               // 3*7 (dz,dy) rows
constexpr int WSTR  = WROWS * 8;        // 168 floats per w: 21 rows x 8 (7 taps + pad)
constexpr float EPSf = 1e-6f;

typedef short bf16x8 __attribute__((ext_vector_type(8)));
typedef float f32x4  __attribute__((ext_vector_type(4)));

static __device__ __forceinline__ short f2bf(float f) {
    __hip_bfloat16 h = __float2bfloat16(f);   // RNE
    short s;
    __builtin_memcpy(&s, &h, 2);
    return s;
}

// ---------------------------------------------------------------------------
// k_twp: pack W_proj into MFMA B-fragment order (bf16).
// ---------------------------------------------------------------------------
__global__ __launch_bounds__(256) void k_twp(
    const float* __restrict__ Wp, short* __restrict__ Wpfrag)
{
    int gid = blockIdx.x * 256 + threadIdx.x;   // < 9*4*64 = 2304
    if (gid >= 9 * 4 * 64) return;
    int lane = gid & 63;
    int kb   = (gid >> 6) & 3;
    int nt   = gid >> 8;
    int n = nt * 16 + (lane & 15);
    int c0 = kb * 32 + (lane >> 4) * 8;
#pragma unroll
    for (int j = 0; j < 8; ++j)
        Wpfrag[(size_t)gid * 8 + j] = f2bf(Wp[n * CIN + c0 + j]);
}

// ---------------------------------------------------------------------------
// Zero only the halo of vcl.
// ---------------------------------------------------------------------------
__global__ __launch_bounds__(256) void k_zero(float* __restrict__ vcl)
{
    int gid  = blockIdx.x * 256 + threadIdx.x;
    int cell = gid >> 5;
    int ch4  = gid & 31;
    if (cell >= PCELLS) return;
    int rb = cell;
    int wp = rb % VPW; rb /= VPW;
    int hp = rb % VPH; rb /= VPH;
    int tp = rb % VPT;
    if (tp >= 1 && tp <= 8 && hp >= 3 && hp <= 58 && wp >= 3 && wp <= 58) return;
    float4 z = {0.f, 0.f, 0.f, 0.f};
    *reinterpret_cast<float4*>(vcl + (size_t)cell * 128 + ch4 * 4) = z;
}

// ---------------------------------------------------------------------------
// k_proj (MFMA): unchanged from R7.
// ---------------------------------------------------------------------------
__global__ __launch_bounds__(256) void k_proj(
    const float* __restrict__ x, const short* __restrict__ Wpfrag,
    float* __restrict__ qn, float* __restrict__ vcl)
{
    int tid  = threadIdx.x;
    int lane = tid & 63;
    int wv   = tid >> 6;
    int bid  = blockIdx.x;                 // < NB * S/128 = 392
    int b    = bid / (S / 128);
    int pbas = (bid - b * (S / 128)) * 128 + wv * 32;

    const float* xb = x + (size_t)b * CIN * S;
    int row = lane & 15;
    int g   = lane >> 4;

    bf16x8 a[2][4];
#pragma unroll
    for (int m = 0; m < 2; ++m) {
        int p = pbas + m * 16 + row;
#pragma unroll
        for (int kb = 0; kb < 4; ++kb) {
            const float* xs = xb + (size_t)(kb * 32 + g * 8) * S + p;
#pragma unroll
            for (int j = 0; j < 8; ++j)
                a[m][kb][j] = f2bf(xs[(size_t)j * S]);
        }
    }

    f32x4 acc[2][9];
#pragma unroll
    for (int m = 0; m < 2; ++m)
#pragma unroll
        for (int nt = 0; nt < 9; ++nt) acc[m][nt] = {0.f, 0.f, 0.f, 0.f};

    const bf16x8* bf = reinterpret_cast<const bf16x8*>(Wpfrag);
#pragma unroll
    for (int nt = 0; nt < 9; ++nt) {
#pragma unroll
        for (int kb = 0; kb < 4; ++kb) {
            bf16x8 bfr = bf[(nt * 4 + kb) * 64 + lane];
            acc[0][nt] = __builtin_amdgcn_mfma_f32_16x16x32_bf16(
                a[0][kb], bfr, acc[0][nt], 0, 0, 0);
            acc[1][nt] = __builtin_amdgcn_mfma_f32_16x16x32_bf16(
                a[1][kb], bfr, acc[1][nt], 0, 0, 0);
        }
    }

#pragma unroll
    for (int m = 0; m < 2; ++m) {
        float sq[4], sv[4];
#pragma unroll
        for (int r = 0; r < 4; ++r) {
            sq[r] = acc[m][0][r] * acc[m][0][r];
            float s = 0.f;
#pragma unroll
            for (int nt = 1; nt < 9; ++nt) s += acc[m][nt][r] * acc[m][nt][r];
            sv[r] = s;
        }
#pragma unroll
        for (int d = 1; d < 16; d <<= 1) {
#pragma unroll
            for (int r = 0; r < 4; ++r) {
                sq[r] += __shfl_xor(sq[r], d, 64);
                sv[r] += __shfl_xor(sv[r], d, 64);
            }
        }
#pragma unroll
        for (int r = 0; r < 4; ++r) {
            int p = pbas + m * 16 + 4 * g + r;
            float qsc = 1.0f / sqrtf(sq[r] + EPSf);
            float vsc = 1.0f / sqrtf(sv[r] + EPSf);
            qn[((size_t)b * DK + (lane & 15)) * S + p] = acc[m][0][r] * qsc;
            int t  = p / (HH * WW);
            int hw = p - t * (HH * WW);
            int h  = hw / WW;
            int w  = hw - h * WW;
            float* vd = vcl
                + (((size_t)(b * VPT + t + 1) * VPH + (h + 3)) * VPW + (w + 3)) * 128
                + (lane & 15);
#pragma unroll
            for (int nt = 1; nt < 9; ++nt)
                vd[(nt - 1) * 16] = acc[m][nt][r] * vsc;
        }
    }
}

// ---------------------------------------------------------------------------
// k_out: block = (b,t,h) row, 256 threads = 4 waves.
//   Phase 1: weff into LDS, layout [w][row:21][8] (7 taps + pad, 32B aligned).
//   Phase 2: thread = (cc: 4 channels, wt: 7 outputs). Per (dz,dy) row:
//     13 float4 v-loads held live (deep MLP), weff via 2x ds_read_b128 per
//     output (half-wave-uniform broadcast), k-outer FMA order.
//   __launch_bounds__(256,4): VGPR cap 128 so the 13 loads stay in flight.
// ---------------------------------------------------------------------------
__global__ __launch_bounds__(256, 4) void k_out(
    const float* __restrict__ vcl, const float* __restrict__ qn,
    const float* __restrict__ wh2, float* __restrict__ out)
{
    __shared__ float weff[WW * WSTR];    // 56*168*4 = 36.75 KB

    int tid = threadIdx.x;
    // XCD-chunked swizzle: 896 = 8 * 112
    int bid = blockIdx.x;
    int nid = (bid & 7) * 112 + (bid >> 3);
    int b   = nid / 448;
    int rem = nid - b * 448;
    int t   = rem / 56, h = rem - t * 56;
    int pbase = t * (HH * WW) + h * WW;

    // Phase 1: weff[w][row][d] = sum_k q[k,w] * wh2[k][row*7+d]
    if (tid < 224) {
        int w = tid % 56, q4 = tid / 56;
        float qr[DK];
#pragma unroll
        for (int k = 0; k < DK; ++k)
            qr[k] = qn[((size_t)b * DK + k) * S + pbase + w];
#pragma unroll 1
        for (int tap = q4; tap < TAPS; tap += 4) {
            float a = 0.f;
#pragma unroll
            for (int k = 0; k < DK; ++k)
                a = fmaf(qr[k], wh2[k * TAPS + tap], a);
            int row = tap / 7, d = tap - row * 7;
            weff[w * WSTR + row * 8 + d] = a;
        }
    }
    __syncthreads();

    int cc = tid & 31;       // 32 chunks x 4 channels = 128
    int wt = tid >> 5;       // 8 tiles x 7 outputs    = 56
    int wbase = wt * 7;

    const float* vbase = vcl
        + ((size_t)(b * VPT + t) * VPH + h) * VPW * 128
        + (size_t)wbase * 128 + cc * 4;
    const float* wtile = &weff[wbase * WSTR];

    float acc[7][4];
#pragma unroll
    for (int k = 0; k < 7; ++k)
#pragma unroll
        for (int j = 0; j < 4; ++j) acc[k][j] = 0.f;

#pragma unroll 1
    for (int dz = 0; dz < 3; ++dz) {
#pragma unroll 1
        for (int dy = 0; dy < 7; ++dy) {
            const float* vr = vbase + (size_t)((dz * VPH + dy) * VPW) * 128;
            int rowo = (dz * 7 + dy) * 8;
            // all 13 row loads issued up-front, held live
            float4 vj[13];
#pragma unroll
            for (int j = 0; j < 13; ++j)
                vj[j] = *reinterpret_cast<const float4*>(vr + j * 128);
#pragma unroll
            for (int k = 0; k < 7; ++k) {
                // 7 taps for output k: 2x b128 from 32B-aligned LDS
                float wk[8];
                *reinterpret_cast<float4*>(&wk[0]) =
                    *reinterpret_cast<const float4*>(&wtile[k * WSTR + rowo]);
                *reinterpret_cast<float4*>(&wk[4]) =
                    *reinterpret_cast<const float4*>(&wtile[k * WSTR + rowo + 4]);
#pragma unroll
                for (int d = 0; d < 7; ++d) {
                    float wv = wk[d];
                    acc[k][0] = fmaf(wv, vj[k + d].x, acc[k][0]);
                    acc[k][1] = fmaf(wv, vj[k + d].y, acc[k][1]);
                    acc[k][2] = fmaf(wv, vj[k + d].z, acc[k][2]);
                    acc[k][3] = fmaf(wv, vj[k + d].w, acc[k][3]);
                }
            }
        }
    }

    size_t ob = ((size_t)b * DV + cc * 4) * S + pbase + wbase;
#pragma unroll
    for (int j = 0; j < 4; ++j)
#pragma unroll
        for (int k = 0; k < 7; ++k)
            out[ob + (size_t)j * S + k] = acc[k][j];
}

// ---------------------------------------------------------------------------
extern "C" void kernel_launch(void* const* d_in, const int* in_sizes, int n_in,
                              void* d_out, int out_size, void* d_ws, size_t ws_size,
                              hipStream_t stream)
{
    const float* x   = (const float*)d_in[0];   // (2,128,8,56,56)
    const float* Wp  = (const float*)d_in[1];   // (144,128)
    const float* wh2 = (const float*)d_in[2];   // (16,1,3,7,7) -> [k][147]
    float* out = (float*)d_out;                 // (2,128,8,56,56)

    float* ws     = (float*)d_ws;
    short* Wpfrag = (short*)ws;                        //  18,432 shorts
    float* qn     = ws + 9216;                         // NB*DK*S
    float* vcl    = qn + (size_t)NB * DK * S;          // padded channel-last v

    k_twp <<<dim3(9), dim3(256), 0, stream>>>(Wp, Wpfrag);
    k_zero<<<dim3((PCELLS * 32 + 255) / 256), dim3(256), 0, stream>>>(vcl);
    k_proj<<<dim3(NB * S / 128), dim3(256), 0, stream>>>(x, Wpfrag, qn, vcl);
    k_out <<<dim3(NB * TT * HH), dim3(256), 0, stream>>>(vcl, qn, wh2, out);
}

// Round 9
// 126.865 us; speedup vs baseline: 1.3308x; 1.3308x over previous
//
#include <hip/hip_runtime.h>
#include <hip/hip_bf16.h>

constexpr int NB   = 2;
constexpr int CIN  = 128;
constexpr int TT   = 8;
constexpr int HH   = 56;
constexpr int WW   = 56;
constexpr int S    = TT * HH * WW;      // 25088
constexpr int DK   = 16;
constexpr int DV   = 128;
constexpr int TAPS = 147;               // 3*7*7
constexpr int NOUT = DK + DV;           // 144
// padded channel-last v: [b][t:10][h:62][w:62][c:128]
constexpr int VPT = 10, VPH = 62, VPW = 62;
constexpr int PCELLS = NB * VPT * VPH * VPW;   // 76880 padded cells
constexpr float EPSf = 1e-6f;

typedef short bf16x8 __attribute__((ext_vector_type(8)));
typedef float f32x4  __attribute__((ext_vector_type(4)));

static __device__ __forceinline__ short f2bf(float f) {
    __hip_bfloat16 h = __float2bfloat16(f);   // RNE
    short s;
    __builtin_memcpy(&s, &h, 2);
    return s;
}

// ---------------------------------------------------------------------------
// k_twp: pack W_proj into MFMA B-fragment order (bf16).  (unchanged)
// ---------------------------------------------------------------------------
__global__ __launch_bounds__(256) void k_twp(
    const float* __restrict__ Wp, short* __restrict__ Wpfrag)
{
    int gid = blockIdx.x * 256 + threadIdx.x;   // < 9*4*64 = 2304
    if (gid >= 9 * 4 * 64) return;
    int lane = gid & 63;
    int kb   = (gid >> 6) & 3;
    int nt   = gid >> 8;
    int n = nt * 16 + (lane & 15);
    int c0 = kb * 32 + (lane >> 4) * 8;
#pragma unroll
    for (int j = 0; j < 8; ++j)
        Wpfrag[(size_t)gid * 8 + j] = f2bf(Wp[n * CIN + c0 + j]);
}

// ---------------------------------------------------------------------------
// Zero only the halo of vcl.  (unchanged)
// ---------------------------------------------------------------------------
__global__ __launch_bounds__(256) void k_zero(float* __restrict__ vcl)
{
    int gid  = blockIdx.x * 256 + threadIdx.x;
    int cell = gid >> 5;
    int ch4  = gid & 31;
    if (cell >= PCELLS) return;
    int rb = cell;
    int wp = rb % VPW; rb /= VPW;
    int hp = rb % VPH; rb /= VPH;
    int tp = rb % VPT;
    if (tp >= 1 && tp <= 8 && hp >= 3 && hp <= 58 && wp >= 3 && wp <= 58) return;
    float4 z = {0.f, 0.f, 0.f, 0.f};
    *reinterpret_cast<float4*>(vcl + (size_t)cell * 128 + ch4 * 4) = z;
}

// ---------------------------------------------------------------------------
// k_proj (MFMA): unchanged from R7.
// ---------------------------------------------------------------------------
__global__ __launch_bounds__(256) void k_proj(
    const float* __restrict__ x, const short* __restrict__ Wpfrag,
    float* __restrict__ qn, float* __restrict__ vcl)
{
    int tid  = threadIdx.x;
    int lane = tid & 63;
    int wv   = tid >> 6;
    int bid  = blockIdx.x;                 // < NB * S/128 = 392
    int b    = bid / (S / 128);
    int pbas = (bid - b * (S / 128)) * 128 + wv * 32;

    const float* xb = x + (size_t)b * CIN * S;
    int row = lane & 15;
    int g   = lane >> 4;

    bf16x8 a[2][4];
#pragma unroll
    for (int m = 0; m < 2; ++m) {
        int p = pbas + m * 16 + row;
#pragma unroll
        for (int kb = 0; kb < 4; ++kb) {
            const float* xs = xb + (size_t)(kb * 32 + g * 8) * S + p;
#pragma unroll
            for (int j = 0; j < 8; ++j)
                a[m][kb][j] = f2bf(xs[(size_t)j * S]);
        }
    }

    f32x4 acc[2][9];
#pragma unroll
    for (int m = 0; m < 2; ++m)
#pragma unroll
        for (int nt = 0; nt < 9; ++nt) acc[m][nt] = {0.f, 0.f, 0.f, 0.f};

    const bf16x8* bf = reinterpret_cast<const bf16x8*>(Wpfrag);
#pragma unroll
    for (int nt = 0; nt < 9; ++nt) {
#pragma unroll
        for (int kb = 0; kb < 4; ++kb) {
            bf16x8 bfr = bf[(nt * 4 + kb) * 64 + lane];
            acc[0][nt] = __builtin_amdgcn_mfma_f32_16x16x32_bf16(
                a[0][kb], bfr, acc[0][nt], 0, 0, 0);
            acc[1][nt] = __builtin_amdgcn_mfma_f32_16x16x32_bf16(
                a[1][kb], bfr, acc[1][nt], 0, 0, 0);
        }
    }

#pragma unroll
    for (int m = 0; m < 2; ++m) {
        float sq[4], sv[4];
#pragma unroll
        for (int r = 0; r < 4; ++r) {
            sq[r] = acc[m][0][r] * acc[m][0][r];
            float s = 0.f;
#pragma unroll
            for (int nt = 1; nt < 9; ++nt) s += acc[m][nt][r] * acc[m][nt][r];
            sv[r] = s;
        }
#pragma unroll
        for (int d = 1; d < 16; d <<= 1) {
#pragma unroll
            for (int r = 0; r < 4; ++r) {
                sq[r] += __shfl_xor(sq[r], d, 64);
                sv[r] += __shfl_xor(sv[r], d, 64);
            }
        }
#pragma unroll
        for (int r = 0; r < 4; ++r) {
            int p = pbas + m * 16 + 4 * g + r;
            float qsc = 1.0f / sqrtf(sq[r] + EPSf);
            float vsc = 1.0f / sqrtf(sv[r] + EPSf);
            qn[((size_t)b * DK + (lane & 15)) * S + p] = acc[m][0][r] * qsc;
            int t  = p / (HH * WW);
            int hw = p - t * (HH * WW);
            int h  = hw / WW;
            int w  = hw - h * WW;
            float* vd = vcl
                + (((size_t)(b * VPT + t + 1) * VPH + (h + 3)) * VPW + (w + 3)) * 128
                + (lane & 15);
#pragma unroll
            for (int nt = 1; nt < 9; ++nt)
                vd[(nt - 1) * 16] = acc[m][nt][r] * vsc;
        }
    }
}

// ---------------------------------------------------------------------------
// k_out: block = (b,t,h) row, 256 threads = 4 waves.
//   Phase 1: wexp[wt][row:21][k:7][d:8] = weff permuted per output-tile
//            (pure reorder, computed directly; pad d to 8 for b128 reads).
//   Phase 2: thread = (cc: 4 channels, wt: 7 outputs). Per (dz,dy) row:
//     sliding 8-slot v window (1 prefetch/k-step, all indices static),
//     taps of output k read as 2x ds_read_b128 (broadcast, conflict-free).
// ---------------------------------------------------------------------------
__global__ __launch_bounds__(256, 2) void k_out(
    const float* __restrict__ vcl, const float* __restrict__ qn,
    const float* __restrict__ wh2, float* __restrict__ out)
{
    __shared__ float wexp[8 * 21 * 7 * 8];   // 9408 floats = 36.75 KB

    int tid = threadIdx.x;
    // XCD-chunked swizzle: 896 = 8 * 112
    int bid = blockIdx.x;
    int nid = (bid & 7) * 112 + (bid >> 3);
    int b   = nid / 448;
    int rem = nid - b * 448;
    int t   = rem / 56, h = rem - t * 56;
    int pbase = t * (HH * WW) + h * WW;

    // Phase 1: wexp[((wt*21+row)*7+k)*8 + d] = sum_kk q[kk][wt*7+k]*wh2[kk][row*7+d]
    const float* qb = qn + (size_t)b * DK * S + pbase;
#pragma unroll 1
    for (int e = tid; e < 9408; e += 256) {
        int d = e & 7;
        if (d < 7) {
            int r1  = e >> 3;          // (wt*21+row)*7 + k
            int k   = r1 % 7;
            int r2  = r1 / 7;          // wt*21 + row
            int row = r2 % 21;
            int wt  = r2 / 21;
            int w   = wt * 7 + k;
            int tap = row * 7 + d;
            float a = 0.f;
#pragma unroll
            for (int kk = 0; kk < DK; ++kk)
                a = fmaf(qb[(size_t)kk * S + w], wh2[kk * TAPS + tap], a);
            wexp[e] = a;
        }
    }
    __syncthreads();

    int cc = tid & 31;       // 32 chunks x 4 channels = 128
    int wt = tid >> 5;       // 8 tiles x 7 outputs    = 56
    int wbase = wt * 7;

    const float* vbase = vcl
        + ((size_t)(b * VPT + t) * VPH + h) * VPW * 128
        + (size_t)wbase * 128 + cc * 4;
    const float* wtile = &wexp[wt * 1176];    // 21*7*8 per tile

    float acc[7][4];
#pragma unroll
    for (int k = 0; k < 7; ++k)
#pragma unroll
        for (int j = 0; j < 4; ++j) acc[k][j] = 0.f;

#pragma unroll 1
    for (int dz = 0; dz < 3; ++dz) {
#pragma unroll 1
        for (int dy = 0; dy < 7; ++dy) {
            const float* vr = vbase + (size_t)((dz * VPH + dy) * VPW) * 128;
            const float* wrow = wtile + (dz * 7 + dy) * 56;   // [k:7][d:8]

            float4 vj[8];
#pragma unroll
            for (int j = 0; j < 7; ++j)
                vj[j] = *reinterpret_cast<const float4*>(vr + j * 128);

#pragma unroll
            for (int k = 0; k < 7; ++k) {
                if (k < 6)   // prefetch column k+7 into the free slot
                    vj[(k + 7) & 7] =
                        *reinterpret_cast<const float4*>(vr + (k + 7) * 128);
                float wk[8];
                *reinterpret_cast<float4*>(&wk[0]) =
                    *reinterpret_cast<const float4*>(wrow + k * 8);
                *reinterpret_cast<float4*>(&wk[4]) =
                    *reinterpret_cast<const float4*>(wrow + k * 8 + 4);
#pragma unroll
                for (int d = 0; d < 7; ++d) {
                    float wv = wk[d];
                    float4 vv = vj[(k + d) & 7];
                    acc[k][0] = fmaf(wv, vv.x, acc[k][0]);
                    acc[k][1] = fmaf(wv, vv.y, acc[k][1]);
                    acc[k][2] = fmaf(wv, vv.z, acc[k][2]);
                    acc[k][3] = fmaf(wv, vv.w, acc[k][3]);
                }
            }
        }
    }

    size_t ob = ((size_t)b * DV + cc * 4) * S + pbase + wbase;
#pragma unroll
    for (int j = 0; j < 4; ++j)
#pragma unroll
        for (int k = 0; k < 7; ++k)
            out[ob + (size_t)j * S + k] = acc[k][j];
}

// ---------------------------------------------------------------------------
extern "C" void kernel_launch(void* const* d_in, const int* in_sizes, int n_in,
                              void* d_out, int out_size, void* d_ws, size_t ws_size,
                              hipStream_t stream)
{
    const float* x   = (const float*)d_in[0];   // (2,128,8,56,56)
    const float* Wp  = (const float*)d_in[1];   // (144,128)
    const float* wh2 = (const float*)d_in[2];   // (16,1,3,7,7) -> [k][147]
    float* out = (float*)d_out;                 // (2,128,8,56,56)

    float* ws     = (float*)d_ws;
    short* Wpfrag = (short*)ws;                        //  18,432 shorts
    float* qn     = ws + 9216;                         // NB*DK*S
    float* vcl    = qn + (size_t)NB * DK * S;          // padded channel-last v

    k_twp <<<dim3(9), dim3(256), 0, stream>>>(Wp, Wpfrag);
    k_zero<<<dim3((PCELLS * 32 + 255) / 256), dim3(256), 0, stream>>>(vcl);
    k_proj<<<dim3(NB * S / 128), dim3(256), 0, stream>>>(x, Wpfrag, qn, vcl);
    k_out <<<dim3(NB * TT * HH), dim3(256), 0, stream>>>(vcl, qn, wh2, out);
}

// Round 10
// 115.234 us; speedup vs baseline: 1.4651x; 1.1009x over previous
//
#include <hip/hip_runtime.h>
#include <hip/hip_bf16.h>

constexpr int NB   = 2;
constexpr int CIN  = 128;
constexpr int TT   = 8;
constexpr int HH   = 56;
constexpr int WW   = 56;
constexpr int S    = TT * HH * WW;      // 25088
constexpr int DK   = 16;
constexpr int DV   = 128;
constexpr int TAPS = 147;               // 3*7*7
constexpr int NOUT = DK + DV;           // 144
// bf16 channel-first padded v: [b][c:128][t:10][h:62][w:64]
constexpr int VPT = 10, VPH = 62, VPWA = 64;
constexpr int PLANE_A = VPT * VPH * VPWA;     // 39680 bf16 per channel
constexpr int BSTR = 72;                      // Band w' stride (shorts): 144B rows, 2-way banks
constexpr float EPSf = 1e-6f;

typedef short bf16x8 __attribute__((ext_vector_type(8)));
typedef float f32x4  __attribute__((ext_vector_type(4)));

static __device__ __forceinline__ short f2bf(float f) {
    __hip_bfloat16 h = __float2bfloat16(f);   // RNE
    short s;
    __builtin_memcpy(&s, &h, 2);
    return s;
}

// ---------------------------------------------------------------------------
// k_twp: pack W_proj into MFMA A-fragment order (bf16).
// Frag (mt, kb): lane l holds A[m = mt*16+(l&15)][k = kb*32+(l>>4)*8+j]
// with A[c_out][cin] = Wp[c_out][cin].   (identical packing to R7)
// ---------------------------------------------------------------------------
__global__ __launch_bounds__(256) void k_twp(
    const float* __restrict__ Wp, short* __restrict__ Wpfrag)
{
    int gid = blockIdx.x * 256 + threadIdx.x;   // < 9*4*64 = 2304
    if (gid >= 9 * 4 * 64) return;
    int lane = gid & 63;
    int kb   = (gid >> 6) & 3;
    int mt   = gid >> 8;
    int n = mt * 16 + (lane & 15);
    int c0 = kb * 32 + (lane >> 4) * 8;
#pragma unroll
    for (int j = 0; j < 8; ++j)
        Wpfrag[(size_t)gid * 8 + j] = f2bf(Wp[n * CIN + c0 + j]);
}

// ---------------------------------------------------------------------------
// k_proj (MFMA, swapped roles): D[m=c_out][n=pos] = sum_cin Wp[c_out][cin]*x[cin][pos]
// Block = 256 thr = 4 waves; wave owns 32 positions (2 N-tiles).
// A = Wpfrag (L2-hot b128), B = x gathered per-lane (64 scalar dwords, as R7).
// Epilogue: norms reduce over lane bits 4,5; q stores coalesced fp32;
// v stores = coalesced-in-w u16 into channel-first padded bf16 layout.
// ---------------------------------------------------------------------------
__global__ __launch_bounds__(256) void k_proj(
    const float* __restrict__ x, const short* __restrict__ Wpfrag,
    float* __restrict__ qn, short* __restrict__ vclb)
{
    int tid  = threadIdx.x;
    int lane = tid & 63;
    int wv   = tid >> 6;
    int bid  = blockIdx.x;                 // < NB * S/128 = 392
    int b    = bid / (S / 128);
    int pbas = (bid - b * (S / 128)) * 128 + wv * 32;

    const float* xb = x + (size_t)b * CIN * S;
    int col = lane & 15;
    int g   = lane >> 4;

    // B-frags from x: bx[n2][kb], lane holds B[k=kb*32+g*8+j][n=pos]
    bf16x8 bx[2][4];
#pragma unroll
    for (int n2 = 0; n2 < 2; ++n2) {
        int p = pbas + n2 * 16 + col;
#pragma unroll
        for (int kb = 0; kb < 4; ++kb) {
            const float* xs = xb + (size_t)(kb * 32 + g * 8) * S + p;
#pragma unroll
            for (int j = 0; j < 8; ++j)
                bx[n2][kb][j] = f2bf(xs[(size_t)j * S]);
        }
    }

    f32x4 acc[9][2];
#pragma unroll
    for (int mt = 0; mt < 9; ++mt) {
        acc[mt][0] = {0.f, 0.f, 0.f, 0.f};
        acc[mt][1] = {0.f, 0.f, 0.f, 0.f};
    }

    const bf16x8* wf = reinterpret_cast<const bf16x8*>(Wpfrag);
#pragma unroll
    for (int mt = 0; mt < 9; ++mt) {
#pragma unroll
        for (int kb = 0; kb < 4; ++kb) {
            bf16x8 aw = wf[(mt * 4 + kb) * 64 + lane];
            acc[mt][0] = __builtin_amdgcn_mfma_f32_16x16x32_bf16(
                aw, bx[0][kb], acc[mt][0], 0, 0, 0);
            acc[mt][1] = __builtin_amdgcn_mfma_f32_16x16x32_bf16(
                aw, bx[1][kb], acc[mt][1], 0, 0, 0);
        }
    }

    // D layout: n(pos) = col, m(c_out) = mt*16 + 4*g + r
#pragma unroll
    for (int n2 = 0; n2 < 2; ++n2) {
        float ssq = 0.f, ssv = 0.f;
#pragma unroll
        for (int r = 0; r < 4; ++r) ssq += acc[0][n2][r] * acc[0][n2][r];
#pragma unroll
        for (int mt = 1; mt < 9; ++mt)
#pragma unroll
            for (int r = 0; r < 4; ++r) ssv += acc[mt][n2][r] * acc[mt][n2][r];
        ssq += __shfl_xor(ssq, 16, 64);
        ssq += __shfl_xor(ssq, 32, 64);
        ssv += __shfl_xor(ssv, 16, 64);
        ssv += __shfl_xor(ssv, 32, 64);
        float qsc = 1.0f / sqrtf(ssq + EPSf);
        float vsc = 1.0f / sqrtf(ssv + EPSf);

        int p = pbas + n2 * 16 + col;
#pragma unroll
        for (int r = 0; r < 4; ++r)
            qn[((size_t)b * DK + (4 * g + r)) * S + p] = acc[0][n2][r] * qsc;

        int t  = p / (HH * WW);
        int hw = p - t * (HH * WW);
        int h  = hw / WW;
        int w  = hw - h * WW;
        size_t pp = (size_t)(t + 1) * (VPH * VPWA) + (size_t)(h + 3) * VPWA + (w + 3);
        short* vb = vclb + (size_t)b * 128 * PLANE_A + pp;
#pragma unroll
        for (int mt = 1; mt < 9; ++mt)
#pragma unroll
            for (int r = 0; r < 4; ++r) {
                int c = (mt - 1) * 16 + 4 * g + r;
                vb[(size_t)c * PLANE_A] = f2bf(acc[mt][n2][r] * vsc);
            }
    }
}

// ---------------------------------------------------------------------------
// k_out (banded MFMA): per (b,t,h) row, out[c][w] = sum_{row,w'} V[c][w']*Band_row[w][w']
//   Phase 1: weff (bf16) into LDS [w][row:21][8], as R5.
//   Loop 21 band-rows: MFMA 128x64x56 (2 Ktiles x 4 Ntiles x 2 Mtiles/wave)
//   on double-buffered LDS Band [64][72] bf16 (same 392 slots rewritten per
//   row; rest stays zero). A-frags = contiguous b128 from channel-first vclb.
// ---------------------------------------------------------------------------
__global__ __launch_bounds__(256) void k_out(
    const short* __restrict__ vclb, const float* __restrict__ qn,
    const float* __restrict__ wh2, float* __restrict__ out)
{
    __shared__ short weff_b[56 * 168];            // [w][row21][8] bf16, 18816 B
    __shared__ char  upool[2 * 64 * BSTR * 2];    // q_s (phase1) then Band dbuf, 18432 B

    int tid  = threadIdx.x;
    int lane = tid & 63;
    int wv   = tid >> 6;
    // XCD-chunked swizzle: 896 = 8 * 112
    int bid = blockIdx.x;
    int nid = (bid & 7) * 112 + (bid >> 3);
    int b   = nid / 448;
    int rem = nid - b * 448;
    int t   = rem / 56, h = rem - t * 56;
    int pbase = t * (HH * WW) + h * WW;

    // ---- Phase 1a: stage q row
    float* q_s = reinterpret_cast<float*>(upool);
    for (int i = tid; i < DK * WW; i += 256) {
        int k = i / 56, w = i - k * 56;
        q_s[i] = qn[((size_t)b * DK + k) * S + pbase + w];
    }
    __syncthreads();

    // ---- Phase 1b: weff[w][row][d] (bf16)
    if (tid < 224) {
        int w = tid % 56, q4 = tid / 56;
        float qr[DK];
#pragma unroll
        for (int k = 0; k < DK; ++k) qr[k] = q_s[k * 56 + w];
#pragma unroll 1
        for (int tap = q4; tap < TAPS; tap += 4) {
            float a = 0.f;
#pragma unroll
            for (int k = 0; k < DK; ++k)
                a = fmaf(qr[k], wh2[k * TAPS + tap], a);
            int row = tap / 7, d = tap - row * 7;
            weff_b[w * 168 + row * 8 + d] = f2bf(a);
        }
    }
    __syncthreads();

    // ---- zero Band double-buffer (overlaps q_s; q_s is dead now)
    short* band = reinterpret_cast<short*>(upool);
    {
        int* bi = reinterpret_cast<int*>(band);
        for (int i = tid; i < 2 * 64 * BSTR / 2; i += 256) bi[i] = 0;
    }
    __syncthreads();

    // precomputed build slots (same every row)
    int e1 = tid;                 // < 392 guard below (tid < 256 always valid)
    int w1 = e1 / 7, d1 = e1 - w1 * 7;
    int e2 = tid + 256;
    int w2 = e2 / 7, d2 = e2 - w2 * 7;
    bool has2 = (e2 < 392);
    bool has1 = (e1 < 392);      // always true for 256 threads

    // build row 0 into buf 0
    if (has1) band[w1 * BSTR + w1 + d1] = weff_b[w1 * 168 + d1];
    if (has2) band[w2 * BSTR + w2 + d2] = weff_b[w2 * 168 + d2];
    __syncthreads();

    int col = lane & 15, g = lane >> 4;
    int cbase = wv * 32;                 // wave owns channels cbase..cbase+31

    f32x4 acc[2][4];
#pragma unroll
    for (int m2 = 0; m2 < 2; ++m2)
#pragma unroll
        for (int n = 0; n < 4; ++n) acc[m2][n] = {0.f, 0.f, 0.f, 0.f};

    const short* vb = vclb + (size_t)b * 128 * PLANE_A;

#pragma unroll 1
    for (int r = 0; r < 21; ++r) {
        const short* cur = band + (r & 1) * (64 * BSTR);
        int dz = r / 7, dy = r - dz * 7;
        size_t rowo = (size_t)(t + dz) * (VPH * VPWA) + (size_t)(h + dy) * VPWA;

        // A-frags: V[c][w'] contiguous bf16x8
        bf16x8 av[2][2];
#pragma unroll
        for (int m2 = 0; m2 < 2; ++m2) {
            const short* ap = vb + (size_t)(cbase + m2 * 16 + col) * PLANE_A
                                 + rowo + g * 8;
            av[m2][0] = *reinterpret_cast<const bf16x8*>(ap);
            av[m2][1] = *reinterpret_cast<const bf16x8*>(ap + 32);
        }
        // B-frags: Band[w][w'] rows
        bf16x8 bbf[4][2];
#pragma unroll
        for (int n = 0; n < 4; ++n) {
            const short* bp = cur + (n * 16 + col) * BSTR + g * 8;
            bbf[n][0] = *reinterpret_cast<const bf16x8*>(bp);
            bbf[n][1] = *reinterpret_cast<const bf16x8*>(bp + 32);
        }
#pragma unroll
        for (int n = 0; n < 4; ++n) {
            acc[0][n] = __builtin_amdgcn_mfma_f32_16x16x32_bf16(
                av[0][0], bbf[n][0], acc[0][n], 0, 0, 0);
            acc[0][n] = __builtin_amdgcn_mfma_f32_16x16x32_bf16(
                av[0][1], bbf[n][1], acc[0][n], 0, 0, 0);
            acc[1][n] = __builtin_amdgcn_mfma_f32_16x16x32_bf16(
                av[1][0], bbf[n][0], acc[1][n], 0, 0, 0);
            acc[1][n] = __builtin_amdgcn_mfma_f32_16x16x32_bf16(
                av[1][1], bbf[n][1], acc[1][n], 0, 0, 0);
        }

        // build row r+1 into the other buffer (same slots, rest stays 0)
        if (r < 20) {
            short* nxt = band + ((r + 1) & 1) * (64 * BSTR);
            int ro = (r + 1) * 8;
            if (has1) nxt[w1 * BSTR + w1 + d1] = weff_b[w1 * 168 + ro + d1];
            if (has2) nxt[w2 * BSTR + w2 + d2] = weff_b[w2 * 168 + ro + d2];
        }
        __syncthreads();
    }

    // ---- epilogue: D[m=c][n=w], c = cbase + m2*16 + 4g + r, w = n*16 + col
#pragma unroll
    for (int m2 = 0; m2 < 2; ++m2) {
#pragma unroll
        for (int n = 0; n < 4; ++n) {
            int w = n * 16 + col;
            if (w < 56) {
                size_t ob = ((size_t)b * DV + cbase + m2 * 16 + 4 * g) * S + pbase + w;
#pragma unroll
                for (int rr = 0; rr < 4; ++rr)
                    out[ob + (size_t)rr * S] = acc[m2][n][rr];
            }
        }
    }
}

// ---------------------------------------------------------------------------
extern "C" void kernel_launch(void* const* d_in, const int* in_sizes, int n_in,
                              void* d_out, int out_size, void* d_ws, size_t ws_size,
                              hipStream_t stream)
{
    const float* x   = (const float*)d_in[0];   // (2,128,8,56,56)
    const float* Wp  = (const float*)d_in[1];   // (144,128)
    const float* wh2 = (const float*)d_in[2];   // (16,1,3,7,7) -> [k][147]
    float* out = (float*)d_out;                 // (2,128,8,56,56)

    float* ws     = (float*)d_ws;
    short* Wpfrag = (short*)ws;                        // 18,432 shorts = 36,864 B
    float* qn     = ws + 9216;                         // NB*DK*S fp32
    short* vclb   = (short*)(qn + (size_t)NB * DK * S);// NB*128*PLANE_A bf16

    size_t vclb_bytes = (size_t)NB * 128 * PLANE_A * sizeof(short);  // 20.3 MB

    k_twp <<<dim3(9), dim3(256), 0, stream>>>(Wp, Wpfrag);
    hipMemsetAsync(vclb, 0, vclb_bytes, stream);
    k_proj<<<dim3(NB * S / 128), dim3(256), 0, stream>>>(x, Wpfrag, qn, vclb);
    k_out <<<dim3(NB * TT * HH), dim3(256), 0, stream>>>(vclb, qn, wh2, out);
}